// Round 10
// baseline (207035.620 us; speedup 1.0000x reference)
//
#include <hip/hip_runtime.h>
#include <math.h>

#define S     128
#define STR   129       // LDS matrix column stride (f64)
#define BB    24
#define RR    64
#define MAXIT 100

// ---- per-block workspace layout (bytes) ----
#define OFF_PC     0          // 128*128 f32
#define OFF_FEATS  65536
#define OFF_CAM    131072
#define OFF_MMETA  196608     // 128 lvl * 128 u32 : out | ent<<8 | exo<<16
#define OFF_MCYC   262144     // rotated cycle node list (int)
#define PER_BLOCK  327680
#define OFF_OBJ    ((size_t)PER_BLOCK * BB)     // 24 * 128 * 8
#define OFF_SPAR   (OFF_OBJ + 24576)            // 24 * 100 * 128 u8
#define OFF_ACC    (OFF_SPAR + 307200)          // accAdv f64, accData f64
// ---- probe scratch (measurement only; real pipeline never reads it) ----
#define OFF_PPC    8388608    // 24 * 65536 probe pc
#define OFF_PMETA  9961472    // 24 * (65536 mMeta + 65536 mCyc)
#define OFF_PDUMP  13107200   // dummy sinks (keep probe values live)

// =======================================================================
// Kernel A: unchanged validated prep.
// =======================================================================
__global__ void prep_kernel(const float* __restrict__ s_arc,
                            const float* __restrict__ s_rel,
                            const int* __restrict__ arcs,
                            const int* __restrict__ rels,
                            char* __restrict__ ws) {
    int idx = blockIdx.x * blockDim.x + threadIdx.x;
    if (idx >= BB * S * S) return;
    int b  = idx >> 14;
    int dh = idx & (S * S - 1);
    int d  = dh >> 7;
    int h  = dh & (S - 1);

    float sa = s_arc[idx];
    const float* sr = s_rel + (size_t)idx * RR;
    int arc = arcs[b * S + d];
    int rel = rels[b * S + d];
    int rstar = (d >= 1 && h == arc) ? rel : -1;

    float fm = -INFINITY;
    float bestv = -INFINITY;
    float camv = 0.f, datav = 0.f;
    for (int r = 0; r < RR; ++r) {
        float comb = __fadd_rn(sa, sr[r]);
        if (comb > fm) fm = comb;
        float pen = (r == rstar) ? 0.0f : 1.0f;
        float v = __fadd_rn(pen, comb);
        if (v > bestv) { bestv = v; camv = comb; }
        if (rstar >= 0 && r == rel) datav = comb;
    }

    char* base = ws + (size_t)b * PER_BLOCK;
    ((float*)(base + OFF_FEATS))[dh] = fm;
    ((float*)(base + OFF_CAM))[dh]   = camv;
    ((float*)(base + OFF_PC))[dh] = (d >= 1 && h == d - 1) ? 1.0f : 0.0f;

    if (rstar >= 0) {
        double* accData = (double*)(ws + OFF_ACC + 8);
        atomicAdd(accData, (double)datav);
    }
}

// =======================================================================
// Single-wave CLE state (LDS).
// =======================================================================
struct ShState {
    double mat[S * STR];            // 132096 B
    double cyccost[S];
    int parIdx[S], parNew[S], curOrd[S], ordNew[S], o2n[S], outIdx[S],
        slotC[S], inCyc[S], cycA[S], phat[S], spar[S], resA[S],
        hK[S], hC[S], probeMark[S];
};

__device__ __forceinline__ int gather2(int lo, int hi, int idx) {
    int a = __builtin_amdgcn_ds_bpermute((idx & 63) * 4, lo);
    int b = __builtin_amdgcn_ds_bpermute((idx & 63) * 4, hi);
    return (idx & 64) ? b : a;
}

// Exact CLE level loop + unwind — VALIDATED R4 BODY (34.9 ms baseline).
// PROBE=0: real path, zero additions. PROBE=1: count levels & cycles.
template <int PROBE>
__device__ void cle_levels_t(ShState* sh,
                             unsigned int* __restrict__ mMeta,
                             int* __restrict__ mCyc,
                             int* __restrict__ res,
                             long* cntL, long* cntC)
{
    const int lane = threadIdx.x;
    const double DINF = __builtin_inf();

    int n = S, lvl = 0;
    while (true) {
        // ---- pointer doubling, saving jump tables par^(2^r) ----
        int t0a[8], t1a[8];
        t0a[0] = sh->parIdx[lane];
        t1a[0] = sh->parIdx[lane + 64];
#pragma unroll
        for (int r = 0; r < 7; ++r) {
            int u0 = t0a[r], u1 = t1a[r];
            int g0 = gather2(t0a[r], t1a[r], u0 & 127);
            int g1 = gather2(t0a[r], t1a[r], u1 & 127);
            t0a[r + 1] = (u0 < 0) ? -1 : g0;
            t1a[r + 1] = (u1 < 0) ? -1 : g1;
        }
        int jf0 = t0a[7], jf1 = t1a[7];     // par^128 : -1 iff reaches root
        unsigned long long m0 = __ballot(lane >= 1 && lane < n && jf0 >= 0);
        unsigned long long m1 = __ballot(lane + 64 < n && jf1 >= 0);
        if (m0 == 0 && m1 == 0) break;   // no cycle: done

        if (PROBE) {
            // orbit-min over forward orbit (cycle min for cyclic nodes)
            int mn0 = lane, mn1 = lane + 64;
#pragma unroll
            for (int r = 0; r < 7; ++r) {
                int q0 = t0a[r], q1 = t1a[r];
                int a0 = gather2(mn0, mn1, q0 & 127);
                int a1 = gather2(mn0, mn1, q1 & 127);
                mn0 = (q0 >= 0 && a0 < mn0) ? a0 : mn0;
                mn1 = (q1 >= 0 && a1 < mn1) ? a1 : mn1;
            }
            // cyclic set = image of par^128 over cycle-reaching nodes
            sh->probeMark[lane] = 0; sh->probeMark[lane + 64] = 0;
            if (lane < n && jf0 >= 0) sh->probeMark[jf0 & 127] = 1;
            if (lane + 64 < n && jf1 >= 0) sh->probeMark[jf1 & 127] = 1;
            int cy0 = sh->probeMark[lane], cy1 = sh->probeMark[lane + 64];
            unsigned long long lb0 = __ballot(lane >= 1 && lane < n && cy0 && mn0 == lane);
            unsigned long long lb1 = __ballot(lane + 64 < n && cy1 && mn1 == lane + 64);
            *cntC += __popcll(lb0) + __popcll(lb1);
            *cntL += 1;
            sh->probeMark[lane] = 0; sh->probeMark[lane + 64] = 0;
        }

        int sMin = m0 ? ((int)__ffsll(m0) - 1) : (64 + (int)__ffsll(m1) - 1);
        int c0 = (sMin < 64) ? __shfl(jf0, sMin) : __shfl(jf1, sMin - 64);

        // ---- validated R4 parallel dual walk + rotated list ----
        int w0 = sMin, w1 = sMin, v0 = c0, v1 = c0;
#pragma unroll
        for (int r = 0; r < 6; ++r) {
            int nw0 = gather2(t0a[r], t1a[r], w0);
            int nw1 = gather2(t0a[r], t1a[r], w1);
            int nv0 = gather2(t0a[r], t1a[r], v0);
            int nv1 = gather2(t0a[r], t1a[r], v1);
            bool bit = (lane >> r) & 1;
            w0 = bit ? nw0 : w0;  w1 = bit ? nw1 : w1;
            v0 = bit ? nv0 : v0;  v1 = bit ? nv1 : v1;
        }
        // set1 has l = lane+64: bit 6 always set
        w1 = gather2(t0a[6], t1a[6], w1);
        v1 = gather2(t0a[6], t1a[6], v1);

        // L = cycle length: first l>=1 with v_l == c0
        unsigned long long bl0 = __ballot(lane >= 1 && v0 == c0);
        unsigned long long bl1 = __ballot(v1 == c0);
        int L = bl0 ? ((int)__ffsll(bl0) - 1) : (64 + (int)__ffsll(bl1) - 1);
        // mark cycle membership
        if (lane < L) sh->inCyc[v0 & 127] = 1;
        if (lane + 64 < L) sh->inCyc[v1 & 127] = 1;
        // p = entry distance on sMin's path; e = entry node
        int f0 = sh->inCyc[w0 & 127];
        int f1 = sh->inCyc[w1 & 127];
        unsigned long long pb0 = __ballot(f0 != 0);
        unsigned long long pb1 = __ballot(f1 != 0);
        int p = pb0 ? ((int)__ffsll(pb0) - 1) : (64 + (int)__ffsll(pb1) - 1);
        int e = (p < 64) ? __shfl(w0, p) : __shfl(w1, p - 64);

        // rotated cycle list starting at e (reference order)
        int nxg0 = gather2(w0, w1, lane + 1);
        int nxg1 = gather2(w0, w1, (lane + 65) & 127);
        {
            int l0 = lane;
            if (l0 >= p && l0 < p + L) {
                int i = l0 - p;
                int c = w0 & 127;
                int nn = (i + 1 < L) ? (nxg0 & 127) : e;
                int sc = sh->curOrd[c];
                sh->cycA[i] = c; sh->slotC[i] = sc;
                sh->cyccost[i] = sh->mat[sc * STR + sh->curOrd[nn]];
                mCyc[lvl * S + i] = c;
            }
            int l1 = lane + 64;
            if (l1 >= p && l1 < p + L) {
                int i = l1 - p;
                int c = w1 & 127;
                int nn = (i + 1 < L) ? (nxg1 & 127) : e;
                int sc = sh->curOrd[c];
                sh->cycA[i] = c; sh->slotC[i] = sc;
                sh->cyccost[i] = sh->mat[sc * STR + sh->curOrd[nn]];
                mCyc[lvl * S + i] = c;
            }
        }

        // ---- out list (ascending) via ballot prefix; o2n renumber ----
        int ic0 = sh->inCyc[lane];
        int ic1 = sh->inCyc[lane + 64];
        unsigned long long g0 = __ballot(lane < n && !ic0);
        unsigned long long g1 = __ballot(lane + 64 < n && !ic1);
        int k = __popcll(g0) + __popcll(g1);
        unsigned long long lt = (1ull << lane) - 1ull;
        if (lane < n && !ic0) {
            int pp = __popcll(g0 & lt);
            sh->outIdx[pp] = lane; sh->o2n[lane] = pp;
        }
        if (lane + 64 < n && !ic1) {
            int pp = __popcll(g0) + __popcll(g1 & lt);
            sh->outIdx[pp] = lane + 64; sh->o2n[lane + 64] = pp;
        }
        if (lane == 0) { sh->hK[lvl] = k; sh->hC[lvl] = L; }

        // ---- enter/exit (reads first, writes after: in-order DS pipe) ----
        int supSlot = sh->slotC[0];
        double ev[2], xv[2]; int so[2], np[2];
#pragma unroll
        for (int s2 = 0; s2 < 2; ++s2) {
            int j = lane + s2 * 64;
            ev[s2] = DINF; xv[s2] = DINF; so[s2] = 0; np[s2] = -3;
            if (j < k) {
                int d = sh->outIdx[j];
                int sd = sh->curOrd[d];
                so[s2] = sd;
                // enter: min over cyc of C[out_j, cyc_ci] - cyccost[ci]
                double bv = sh->mat[sh->slotC[0] * STR + sd] - sh->cyccost[0];
                int bi = 0;
                for (int ci = 1; ci < L; ++ci) {
                    double v = sh->mat[sh->slotC[ci] * STR + sd] - sh->cyccost[ci];
                    if (v < bv) { bv = v; bi = ci; }
                }
                ev[s2] = bv;
                // exit: min over cyc of C[cyc_ci, out_j]
                double b2 = sh->mat[sd * STR + sh->slotC[0]];
                int bo = 0;
                for (int ci = 1; ci < L; ++ci) {
                    double v = sh->mat[sd * STR + sh->slotC[ci]];
                    if (v < b2) { b2 = v; bo = ci; }
                }
                xv[s2] = b2;
                sh->ordNew[j] = sd;
                // packed metadata: out | ent<<8 | exo<<16
                mMeta[lvl * S + j] = (unsigned)d | ((unsigned)sh->cycA[bi] << 8)
                                                | ((unsigned)sh->cycA[bo] << 16);
                // incremental par, sup-candidate compare (sound + exact):
                if (j == 0) np[s2] = -1;
                else {
                    int op = sh->parIdx[d];
                    if (sh->inCyc[op]) np[s2] = -2;
                    else {
                        double oldv = sh->mat[sd * STR + sh->curOrd[op]];
                        np[s2] = (b2 < oldv) ? k : sh->o2n[op];
                    }
                }
            }
        }
        // write sup column/row into retired slot of cyc[0]
#pragma unroll
        for (int s2 = 0; s2 < 2; ++s2) {
            int j = lane + s2 * 64;
            if (j < k) {
                sh->mat[supSlot * STR + so[s2]] = ev[s2];
                sh->mat[so[s2] * STR + supSlot] = xv[s2];
            }
        }
        if (lane == 0) { sh->mat[supSlot * STR + supSlot] = DINF; sh->ordNew[k] = supSlot; }

        // sup column par: first-min over ev[0..k-1]
        double rv = (lane < k) ? ev[0] : DINF; int ri = lane;
        {
            double rv1 = (lane + 64 < k) ? ev[1] : DINF;
            if (rv1 < rv) { rv = rv1; ri = lane + 64; }
        }
        for (int off = 32; off; off >>= 1) {
            double ov = __shfl_down(rv, off); int oi = __shfl_down(ri, off);
            if (ov < rv || (ov == rv && oi < ri)) { rv = ov; ri = oi; }
        }
        int supPar = __shfl(ri, 0);

#pragma unroll
        for (int s2 = 0; s2 < 2; ++s2) {
            int j = lane + s2 * 64;
            if (j < k) sh->parNew[j] = np[s2];
        }
        if (lane == 0) sh->parNew[k] = supPar;
        // rescan columns whose old par was in the cycle (exact recompute)
#pragma unroll
        for (int s2 = 0; s2 < 2; ++s2) {
            int j = lane + s2 * 64;
            if (j < k && np[s2] == -2) {
                int sd = so[s2];
                double bv = DINF; int bi = -1;
                for (int h2 = 0; h2 <= k; ++h2) {
                    double v = sh->mat[sd * STR + sh->ordNew[h2]];
                    if (v < bv) { bv = v; bi = h2; }
                }
                sh->parNew[j] = bi;
            }
        }
        // commit
#pragma unroll
        for (int s2 = 0; s2 < 2; ++s2) {
            int i = lane + s2 * 64;
            if (i <= k) { sh->parIdx[i] = sh->parNew[i]; sh->curOrd[i] = sh->ordNew[i]; }
            sh->inCyc[i] = 0;
        }
        n = k + 1; ++lvl;
    }

    // ---- unwind: packed meta, depth-2 named-register prefetch ----
    int r0 = sh->parIdx[lane], r1 = sh->parIdx[lane + 64];
    int l = lvl - 1;
    int mA0=0,mA1=0,cA0=0,cA1=0, mB0=0,mB1=0,cB0=0,cB1=0;
    if (l >= 0) {
        mA0 = mMeta[l*S+lane]; mA1 = mMeta[l*S+lane+64];
        cA0 = mCyc[l*S+lane];  cA1 = mCyc[l*S+lane+64];
    }
    if (l >= 1) {
        mB0 = mMeta[(l-1)*S+lane]; mB1 = mMeta[(l-1)*S+lane+64];
        cB0 = mCyc[(l-1)*S+lane];  cB1 = mCyc[(l-1)*S+lane+64];
    }
#define UNW_STEP(LM0, LM1, LC0, LC1, LVL_)                                    \
    {                                                                         \
        int kl = sh->hK[LVL_], cl = sh->hC[LVL_];                             \
        int hiSup = gather2(r0, r1, kl);                                      \
        int supM = gather2(LM0, LM1, hiSup & 127);                            \
        int u = supM & 255, vE = (supM >> 8) & 255;                           \
        int g0w = gather2(LM0, LM1, r0 & 127);                                \
        int g1w = gather2(LM0, LM1, r1 & 127);                                \
        int gc0 = gather2(LC0, LC1, lane + 1);                                \
        int gc1 = gather2(LC0, LC1, (lane + 65) & 127);                       \
        int c00 = __shfl(LC0, 0);                                             \
        if (lane == 0) sh->resA[0] = -1;                                      \
        if (lane >= 1 && lane < kl)                                           \
            sh->resA[LM0 & 255] = (r0 == kl) ? ((LM0 >> 16) & 255) : (g0w & 255); \
        if (lane + 64 < kl)                                                   \
            sh->resA[LM1 & 255] = (r1 == kl) ? ((LM1 >> 16) & 255) : (g1w & 255); \
        if (lane < cl) {                                                      \
            int c = LC0; int pn = (lane + 1 < cl) ? gc0 : c00;                \
            sh->resA[c & 127] = (c == vE) ? u : pn;                           \
        }                                                                     \
        if (lane + 64 < cl) {                                                 \
            int c = LC1; int pn = (lane + 65 < cl) ? gc1 : c00;               \
            sh->resA[c & 127] = (c == vE) ? u : pn;                           \
        }                                                                     \
        r0 = sh->resA[lane]; r1 = sh->resA[lane + 64];                        \
    }
    while (l >= 0) {
        {
            int lm0 = mA0, lm1 = mA1, lc0 = cA0, lc1 = cA1;
            if (l >= 2) {
                mA0 = mMeta[(l-2)*S+lane]; mA1 = mMeta[(l-2)*S+lane+64];
                cA0 = mCyc[(l-2)*S+lane];  cA1 = mCyc[(l-2)*S+lane+64];
            }
            UNW_STEP(lm0, lm1, lc0, lc1, l)
        }
        --l;
        if (l < 0) break;
        {
            int lm0 = mB0, lm1 = mB1, lc0 = cB0, lc1 = cB1;
            if (l >= 2) {
                mB0 = mMeta[(l-2)*S+lane]; mB1 = mMeta[(l-2)*S+lane+64];
                cB0 = mCyc[(l-2)*S+lane];  cB1 = mCyc[(l-2)*S+lane+64];
            }
            UNW_STEP(lm0, lm1, lc0, lc1, l)
        }
        --l;
    }
#undef UNW_STEP
    res[lane] = r0; res[lane + 64] = r1;
}

// =======================================================================
// FW body shared by real kernel (PROBE=0, real buffers, history stores)
// and probe kernels (PROBE=1, scratch buffers, counts out).
// =======================================================================
template <int PROBE>
__device__ void fw_body(float* pcT, const float* featsT,
                        unsigned int* mMeta, int* mCyc,
                        double* objG, unsigned char* sParG,
                        long* cntL, long* cntC, double* dumpD)
{
    const int lane = threadIdx.x;
    __shared__ ShState sh;

    for (int t = 0; t < MAXIT; ++t) {
        // ---- pass A: fused pc-update(t-1) + mode-0 fill + level-0 argmin ----
        float gamma = (t > 0) ? (float)(2.0 / (double)(t + 1)) : 0.0f;
#pragma unroll
        for (int c2 = 0; c2 < 2; ++c2) {
            int col = lane + 64 * c2;
            int sp = (t > 0) ? sh.spar[col] : -1;
            float* pcc = pcT + col * S;
            double* mcol = sh.mat + col * STR;
            float bv = __builtin_inff(); int bi = -1;
#pragma unroll
            for (int i = 0; i < 32; ++i) {
                float4 q = ((float4*)pcc)[i];
                float v0 = q.x, v1 = q.y, v2 = q.z, v3 = q.w;
#define PA_ELEM(VV, EE)                                                       \
                {                                                             \
                    int h = i * 4 + EE;                                       \
                    float pv = VV;                                            \
                    if (t > 0) {                                              \
                        float sv = (sp == h) ? 1.0f : 0.0f;                   \
                        pv = __fadd_rn(pv, __fmul_rn(gamma, __fsub_rn(sv, pv))); \
                        VV = pv;                                              \
                    }                                                         \
                    if (h == col || col == 0) mcol[h] = __builtin_inf();      \
                    else {                                                    \
                        float cv = -pv;                                       \
                        if (cv < bv) { bv = cv; bi = h; }                     \
                        mcol[h] = -(double)pv;                                \
                    }                                                         \
                }
                PA_ELEM(v0, 0) PA_ELEM(v1, 1) PA_ELEM(v2, 2) PA_ELEM(v3, 3)
#undef PA_ELEM
                if (t > 0) { q.x=v0; q.y=v1; q.z=v2; q.w=v3; ((float4*)pcc)[i] = q; }
            }
            sh.parIdx[col] = (col == 0) ? -1 : bi;
            sh.curOrd[col] = col;
            sh.inCyc[col] = 0;
        }
        // p_hat = mst(-pc)
        cle_levels_t<PROBE>(&sh, mMeta, mCyc, sh.phat, cntL, cntC);

        // ---- pass B: fused obj + grad fill + level-0 argmin ----
        double acc = 0.0;
#pragma unroll
        for (int c2 = 0; c2 < 2; ++c2) {
            int col = lane + 64 * c2;
            int hp = sh.phat[col];
            const float* fc = featsT + col * S;
            const float* pcc = pcT + col * S;
            double* mcol = sh.mat + col * STR;
            float bv = __builtin_inff(); int bi = -1;
#pragma unroll
            for (int i = 0; i < 32; ++i) {
                float4 f4 = ((const float4*)fc)[i];
                float4 p4 = ((const float4*)pcc)[i];
                float fv0=f4.x, fv1=f4.y, fv2=f4.z, fv3=f4.w;
                float pv0=p4.x, pv1=p4.y, pv2=p4.z, pv3=p4.w;
#define PB_ELEM(FV, PV, EE)                                                   \
                {                                                             \
                    int h = i * 4 + EE;                                       \
                    float ph = (hp == h) ? 1.0f : 0.0f;                       \
                    float diff = __fsub_rn(ph, FV);                           \
                    acc += (double)__fmul_rn(diff, PV);                       \
                    if (h == col || col == 0) mcol[h] = __builtin_inf();      \
                    else {                                                    \
                        float g = __fdiv_rn(diff, 24.0f);                     \
                        if (g < bv) { bv = g; bi = h; }                       \
                        mcol[h] = (double)g;                                  \
                    }                                                         \
                }
                PB_ELEM(fv0, pv0, 0) PB_ELEM(fv1, pv1, 1)
                PB_ELEM(fv2, pv2, 2) PB_ELEM(fv3, pv3, 3)
#undef PB_ELEM
            }
            sh.parIdx[col] = (col == 0) ? -1 : bi;
            sh.curOrd[col] = col;
            sh.inCyc[col] = 0;
        }
        for (int off = 32; off; off >>= 1) acc += __shfl_down(acc, off);
        if (lane == 0) {
            if (PROBE) dumpD[t & 1] = acc;   // keep acc live (no DCE)
            else objG[t] = acc;
        }

        // s = mst(grad)
        cle_levels_t<PROBE>(&sh, mMeta, mCyc, sh.spar, cntL, cntC);
        if (!PROBE) {
            sParG[t * S + lane]      = (unsigned char)(sh.spar[lane] & 255);
            sParG[t * S + lane + 64] = (unsigned char)(sh.spar[lane + 64] & 255);
        }
    }
}

// =======================================================================
// Real FW kernel: exact R4 behavior.
// =======================================================================
__global__ void __launch_bounds__(64) fw_kernel(char* __restrict__ ws) {
    const int b = blockIdx.x;
    char* base = ws + (size_t)b * PER_BLOCK;
    long dl = 0, dc = 0;
    fw_body<0>((float*)(base + OFF_PC), (const float*)(base + OFF_FEATS),
               (unsigned int*)(base + OFF_MMETA), (int*)(base + OFF_MCYC),
               (double*)(ws + OFF_OBJ) + (size_t)b * 128,
               (unsigned char*)(ws + OFF_SPAR) + (size_t)b * MAXIT * S,
               &dl, &dc, (double*)0);
}

// =======================================================================
// Probe kernels: identical compute on scratch; duration encodes counts.
// MODE 0 -> spin on total levels; MODE 1 -> spin on total cycles.
// =======================================================================
__device__ __forceinline__ void spin_units(long units) {
    if (units < 0) units = 0;
    if (units > 100000) units = 100000;
    unsigned long long start = __builtin_amdgcn_s_memrealtime();
    unsigned long long target = (unsigned long long)units * 350ull;
    while (__builtin_amdgcn_s_memrealtime() - start < target) { }
}

template <int MODE>
__global__ void __launch_bounds__(64) probe_kernel(char* __restrict__ ws) {
    const int b = blockIdx.x, lane = threadIdx.x;
    float* pcP = (float*)(ws + OFF_PPC + (size_t)b * 65536);
    const float* featsT = (const float*)(ws + (size_t)b * PER_BLOCK + OFF_FEATS);
    unsigned int* mMetaP = (unsigned int*)(ws + OFF_PMETA + (size_t)b * 131072);
    int* mCycP = (int*)(ws + OFF_PMETA + (size_t)b * 131072 + 65536);
    double* dumpD = (double*)(ws + OFF_PDUMP + (size_t)b * 64);

    // init probe pc to the chain
    for (int i = 0; i < (S * S) / 64; ++i) {
        int idx = i * 64 + lane;
        int d = idx >> 7, h = idx & (S - 1);
        pcP[idx] = (d >= 1 && h == d - 1) ? 1.0f : 0.0f;
    }

    long cl = 0, cc = 0;
    fw_body<1>(pcP, featsT, mMetaP, mCycP, (double*)0, (unsigned char*)0,
               &cl, &cc, dumpD);

    if (lane == 0) { dumpD[2] = (double)cl; dumpD[3] = (double)cc; }
    spin_units(MODE == 0 ? cl : cc);
}

// cal: spin exactly 10,000 units -> calibrates realtime tick rate.
__global__ void cal_kernel(char* __restrict__ ws) {
    spin_units(10000);
}

// =======================================================================
// Finalize: t* = first argmin of mean obj; replay pc to t*; loss.
// =======================================================================
__global__ void __launch_bounds__(64) fin_kernel(char* __restrict__ ws) {
    const int b = blockIdx.x, lane = threadIdx.x;
    char* base = ws + (size_t)b * PER_BLOCK;
    const float* camT = (const float*)(base + OFF_CAM);
    const double* objG = (const double*)(ws + OFF_OBJ);
    const unsigned char* sParG =
        (const unsigned char*)(ws + OFF_SPAR) + (size_t)b * MAXIT * S;
    double* accAdv = (double*)(ws + OFF_ACC);

    __shared__ float pcL[S * S];
    __shared__ unsigned char sPL[MAXIT * S];

    double v0 = __builtin_inf(), v1 = __builtin_inf();
    if (lane < MAXIT) {
        double s = 0.0;
        for (int bb = 0; bb < BB; ++bb) s += objG[bb * 128 + lane];
        v0 = s / (double)BB;
    }
    if (lane + 64 < MAXIT) {
        double s = 0.0;
        for (int bb = 0; bb < BB; ++bb) s += objG[bb * 128 + lane + 64];
        v1 = s / (double)BB;
    }
    double bv = v0; int bi = lane;
    if (v1 < bv) { bv = v1; bi = lane + 64; }
    for (int off = 32; off; off >>= 1) {
        double ov = __shfl_down(bv, off); int oi = __shfl_down(bi, off);
        if (ov < bv || (ov == bv && oi < bi)) { bv = ov; bi = oi; }
    }
    int tStar = __shfl(bi, 0);

    for (int wgt = lane; wgt < (MAXIT * S) / 4; wgt += 64)
        ((unsigned int*)sPL)[wgt] = ((const unsigned int*)sParG)[wgt];

    for (int i = 0; i < (S * S) / 64; ++i) {
        int idx = i * 64 + lane;
        int d = idx >> 7, h = idx & (S - 1);
        pcL[idx] = (d >= 1 && h == d - 1) ? 1.0f : 0.0f;
    }
    for (int t = 0; t < tStar; ++t) {
        float gamma = (float)(2.0 / (double)(t + 2));
        for (int d = 0; d < S; ++d) {
            int sp = sPL[t * S + d];
            float p0 = pcL[d * S + lane];
            float p1 = pcL[d * S + lane + 64];
            float sv0 = (sp == lane) ? 1.0f : 0.0f;
            float sv1 = (sp == lane + 64) ? 1.0f : 0.0f;
            pcL[d * S + lane]      = __fadd_rn(p0, __fmul_rn(gamma, __fsub_rn(sv0, p0)));
            pcL[d * S + lane + 64] = __fadd_rn(p1, __fmul_rn(gamma, __fsub_rn(sv1, p1)));
        }
    }
    double part = 0.0;
    for (int i = 0; i < (S * S) / 64; ++i) {
        int idx = i * 64 + lane;
        part += (double)__fmul_rn(pcL[idx], camT[idx]);
    }
    for (int off = 32; off; off >>= 1) part += __shfl_down(part, off);
    if (lane == 0) atomicAdd(accAdv, part);
}

__global__ void fin2_kernel(const char* __restrict__ ws, float* __restrict__ out) {
    if (threadIdx.x == 0) {
        const double* acc = (const double*)(ws + OFF_ACC);
        out[0] = (float)((acc[0] - acc[1]) / (double)BB);
    }
}

extern "C" void kernel_launch(void* const* d_in, const int* in_sizes, int n_in,
                              void* d_out, int out_size, void* d_ws, size_t ws_size,
                              hipStream_t stream) {
    const float* s_arc = (const float*)d_in[0];
    const float* s_rel = (const float*)d_in[1];
    const int*   arcs  = (const int*)d_in[2];
    const int*   rels  = (const int*)d_in[3];
    char* ws = (char*)d_ws;

    hipMemsetAsync(ws + OFF_ACC, 0, 16, stream);
    int total = BB * S * S;
    prep_kernel<<<(total + 255) / 256, 256, 0, stream>>>(s_arc, s_rel, arcs, rels, ws);
    fw_kernel<<<dim3(BB), dim3(64), 0, stream>>>(ws);
    fin_kernel<<<dim3(BB), dim3(64), 0, stream>>>(ws);
    fin2_kernel<<<dim3(1), dim3(64), 0, stream>>>(ws, (float*)d_out);
    // measurement probes (write only to probe scratch; d_out already final)
    probe_kernel<0><<<dim3(BB), dim3(64), 0, stream>>>(ws);
    probe_kernel<1><<<dim3(BB), dim3(64), 0, stream>>>(ws);
    cal_kernel<<<dim3(1), dim3(64), 0, stream>>>(ws);
}

// Round 11
// 35413.022 us; speedup vs baseline: 5.8463x; 5.8463x over previous
//
#include <hip/hip_runtime.h>
#include <math.h>

#define S     128
#define STR   129       // LDS matrix column stride (f64)
#define BB    24
#define RR    64
#define MAXIT 100

// ---- per-block workspace layout (bytes) ----
#define OFF_PC     0          // 128*128 f32
#define OFF_FEATS  65536
#define OFF_CAM    131072
#define OFF_MMETA  196608     // 128 lvl * 128 u32 : out | ent<<8 | exo<<16
#define OFF_MCYC   262144     // rotated cycle node list (int)
#define PER_BLOCK  327680
#define OFF_OBJ    ((size_t)PER_BLOCK * BB)     // 24 * 128 * 8
#define OFF_SPAR   (OFF_OBJ + 24576)            // 24 * 100 * 128 u8
#define OFF_ACC    (OFF_SPAR + 307200)          // accAdv f64, accData f64

// =======================================================================
// Kernel A: unchanged validated prep.
// =======================================================================
__global__ void prep_kernel(const float* __restrict__ s_arc,
                            const float* __restrict__ s_rel,
                            const int* __restrict__ arcs,
                            const int* __restrict__ rels,
                            char* __restrict__ ws) {
    int idx = blockIdx.x * blockDim.x + threadIdx.x;
    if (idx >= BB * S * S) return;
    int b  = idx >> 14;
    int dh = idx & (S * S - 1);
    int d  = dh >> 7;
    int h  = dh & (S - 1);

    float sa = s_arc[idx];
    const float* sr = s_rel + (size_t)idx * RR;
    int arc = arcs[b * S + d];
    int rel = rels[b * S + d];
    int rstar = (d >= 1 && h == arc) ? rel : -1;

    float fm = -INFINITY;
    float bestv = -INFINITY;
    float camv = 0.f, datav = 0.f;
    for (int r = 0; r < RR; ++r) {
        float comb = __fadd_rn(sa, sr[r]);
        if (comb > fm) fm = comb;
        float pen = (r == rstar) ? 0.0f : 1.0f;
        float v = __fadd_rn(pen, comb);
        if (v > bestv) { bestv = v; camv = comb; }
        if (rstar >= 0 && r == rel) datav = comb;
    }

    char* base = ws + (size_t)b * PER_BLOCK;
    ((float*)(base + OFF_FEATS))[dh] = fm;
    ((float*)(base + OFF_CAM))[dh]   = camv;
    ((float*)(base + OFF_PC))[dh] = (d >= 1 && h == d - 1) ? 1.0f : 0.0f;

    if (rstar >= 0) {
        double* accData = (double*)(ws + OFF_ACC + 8);
        atomicAdd(accData, (double)datav);
    }
}

// =======================================================================
// Single-wave CLE state (LDS). Identical to validated R4.
// =======================================================================
struct ShState {
    double mat[S * STR];            // 132096 B
    double cyccost[S];
    int parIdx[S], parNew[S], curOrd[S], ordNew[S], o2n[S], outIdx[S],
        slotC[S], inCyc[S], cycA[S], phat[S], spar[S], resA[S],
        hK[S], hC[S];
};

__device__ __forceinline__ int gather2(int lo, int hi, int idx) {
    int a = __builtin_amdgcn_ds_bpermute((idx & 63) * 4, lo);
    int b = __builtin_amdgcn_ds_bpermute((idx & 63) * 4, hi);
    return (idx & 64) ? b : a;
}

// Exact CLE level loop + unwind — VALIDATED R4 BODY (34.9 ms baseline).
// Latency floor analysis (R10 probes): ~80 levels/CLE x 200 CLE/block
// x ~5.3K-cycle wave-serial dependent chain per level ~= 35 ms; cascade
// is sequential (C/L ~= 1.0-1.3), so batching cannot beat ~1.3x and all
// chain-shaving substitutions measured slower (R7/R8/R9).
__device__ void cle_levels(ShState* sh,
                           unsigned int* __restrict__ mMeta,
                           int* __restrict__ mCyc,
                           int* __restrict__ res)
{
    const int lane = threadIdx.x;
    const double DINF = __builtin_inf();

    int n = S, lvl = 0;
    while (true) {
        // ---- pointer doubling, saving jump tables par^(2^r) ----
        int t0a[8], t1a[8];
        t0a[0] = sh->parIdx[lane];
        t1a[0] = sh->parIdx[lane + 64];
#pragma unroll
        for (int r = 0; r < 7; ++r) {
            int u0 = t0a[r], u1 = t1a[r];
            int g0 = gather2(t0a[r], t1a[r], u0 & 127);
            int g1 = gather2(t0a[r], t1a[r], u1 & 127);
            t0a[r + 1] = (u0 < 0) ? -1 : g0;
            t1a[r + 1] = (u1 < 0) ? -1 : g1;
        }
        int jf0 = t0a[7], jf1 = t1a[7];     // par^128 : -1 iff reaches root
        unsigned long long m0 = __ballot(lane >= 1 && lane < n && jf0 >= 0);
        unsigned long long m1 = __ballot(lane + 64 < n && jf1 >= 0);
        if (m0 == 0 && m1 == 0) break;   // no cycle: done
        int sMin = m0 ? ((int)__ffsll(m0) - 1) : (64 + (int)__ffsll(m1) - 1);
        int c0 = (sMin < 64) ? __shfl(jf0, sMin) : __shfl(jf1, sMin - 64);

        // ---- validated R4 parallel dual walk + rotated list ----
        int w0 = sMin, w1 = sMin, v0 = c0, v1 = c0;
#pragma unroll
        for (int r = 0; r < 6; ++r) {
            int nw0 = gather2(t0a[r], t1a[r], w0);
            int nw1 = gather2(t0a[r], t1a[r], w1);
            int nv0 = gather2(t0a[r], t1a[r], v0);
            int nv1 = gather2(t0a[r], t1a[r], v1);
            bool bit = (lane >> r) & 1;
            w0 = bit ? nw0 : w0;  w1 = bit ? nw1 : w1;
            v0 = bit ? nv0 : v0;  v1 = bit ? nv1 : v1;
        }
        // set1 has l = lane+64: bit 6 always set
        w1 = gather2(t0a[6], t1a[6], w1);
        v1 = gather2(t0a[6], t1a[6], v1);

        // L = cycle length: first l>=1 with v_l == c0
        unsigned long long bl0 = __ballot(lane >= 1 && v0 == c0);
        unsigned long long bl1 = __ballot(v1 == c0);
        int L = bl0 ? ((int)__ffsll(bl0) - 1) : (64 + (int)__ffsll(bl1) - 1);
        // mark cycle membership
        if (lane < L) sh->inCyc[v0 & 127] = 1;
        if (lane + 64 < L) sh->inCyc[v1 & 127] = 1;
        // p = entry distance on sMin's path; e = entry node
        int f0 = sh->inCyc[w0 & 127];
        int f1 = sh->inCyc[w1 & 127];
        unsigned long long pb0 = __ballot(f0 != 0);
        unsigned long long pb1 = __ballot(f1 != 0);
        int p = pb0 ? ((int)__ffsll(pb0) - 1) : (64 + (int)__ffsll(pb1) - 1);
        int e = (p < 64) ? __shfl(w0, p) : __shfl(w1, p - 64);

        // rotated cycle list starting at e (reference order)
        int nxg0 = gather2(w0, w1, lane + 1);
        int nxg1 = gather2(w0, w1, (lane + 65) & 127);
        {
            int l0 = lane;
            if (l0 >= p && l0 < p + L) {
                int i = l0 - p;
                int c = w0 & 127;
                int nn = (i + 1 < L) ? (nxg0 & 127) : e;
                int sc = sh->curOrd[c];
                sh->cycA[i] = c; sh->slotC[i] = sc;
                sh->cyccost[i] = sh->mat[sc * STR + sh->curOrd[nn]];
                mCyc[lvl * S + i] = c;
            }
            int l1 = lane + 64;
            if (l1 >= p && l1 < p + L) {
                int i = l1 - p;
                int c = w1 & 127;
                int nn = (i + 1 < L) ? (nxg1 & 127) : e;
                int sc = sh->curOrd[c];
                sh->cycA[i] = c; sh->slotC[i] = sc;
                sh->cyccost[i] = sh->mat[sc * STR + sh->curOrd[nn]];
                mCyc[lvl * S + i] = c;
            }
        }

        // ---- out list (ascending) via ballot prefix; o2n renumber ----
        int ic0 = sh->inCyc[lane];
        int ic1 = sh->inCyc[lane + 64];
        unsigned long long g0 = __ballot(lane < n && !ic0);
        unsigned long long g1 = __ballot(lane + 64 < n && !ic1);
        int k = __popcll(g0) + __popcll(g1);
        unsigned long long lt = (1ull << lane) - 1ull;
        if (lane < n && !ic0) {
            int pp = __popcll(g0 & lt);
            sh->outIdx[pp] = lane; sh->o2n[lane] = pp;
        }
        if (lane + 64 < n && !ic1) {
            int pp = __popcll(g0) + __popcll(g1 & lt);
            sh->outIdx[pp] = lane + 64; sh->o2n[lane + 64] = pp;
        }
        if (lane == 0) { sh->hK[lvl] = k; sh->hC[lvl] = L; }

        // ---- enter/exit (reads first, writes after: in-order DS pipe) ----
        int supSlot = sh->slotC[0];
        double ev[2], xv[2]; int so[2], np[2];
#pragma unroll
        for (int s2 = 0; s2 < 2; ++s2) {
            int j = lane + s2 * 64;
            ev[s2] = DINF; xv[s2] = DINF; so[s2] = 0; np[s2] = -3;
            if (j < k) {
                int d = sh->outIdx[j];
                int sd = sh->curOrd[d];
                so[s2] = sd;
                // enter: min over cyc of C[out_j, cyc_ci] - cyccost[ci]
                double bv = sh->mat[sh->slotC[0] * STR + sd] - sh->cyccost[0];
                int bi = 0;
                for (int ci = 1; ci < L; ++ci) {
                    double v = sh->mat[sh->slotC[ci] * STR + sd] - sh->cyccost[ci];
                    if (v < bv) { bv = v; bi = ci; }
                }
                ev[s2] = bv;
                // exit: min over cyc of C[cyc_ci, out_j]
                double b2 = sh->mat[sd * STR + sh->slotC[0]];
                int bo = 0;
                for (int ci = 1; ci < L; ++ci) {
                    double v = sh->mat[sd * STR + sh->slotC[ci]];
                    if (v < b2) { b2 = v; bo = ci; }
                }
                xv[s2] = b2;
                sh->ordNew[j] = sd;
                // packed metadata: out | ent<<8 | exo<<16
                mMeta[lvl * S + j] = (unsigned)d | ((unsigned)sh->cycA[bi] << 8)
                                                | ((unsigned)sh->cycA[bo] << 16);
                // incremental par, sup-candidate compare (sound + exact):
                if (j == 0) np[s2] = -1;
                else {
                    int op = sh->parIdx[d];
                    if (sh->inCyc[op]) np[s2] = -2;
                    else {
                        double oldv = sh->mat[sd * STR + sh->curOrd[op]];
                        np[s2] = (b2 < oldv) ? k : sh->o2n[op];
                    }
                }
            }
        }
        // write sup column/row into retired slot of cyc[0]
#pragma unroll
        for (int s2 = 0; s2 < 2; ++s2) {
            int j = lane + s2 * 64;
            if (j < k) {
                sh->mat[supSlot * STR + so[s2]] = ev[s2];
                sh->mat[so[s2] * STR + supSlot] = xv[s2];
            }
        }
        if (lane == 0) { sh->mat[supSlot * STR + supSlot] = DINF; sh->ordNew[k] = supSlot; }

        // sup column par: first-min over ev[0..k-1]
        double rv = (lane < k) ? ev[0] : DINF; int ri = lane;
        {
            double rv1 = (lane + 64 < k) ? ev[1] : DINF;
            if (rv1 < rv) { rv = rv1; ri = lane + 64; }
        }
        for (int off = 32; off; off >>= 1) {
            double ov = __shfl_down(rv, off); int oi = __shfl_down(ri, off);
            if (ov < rv || (ov == rv && oi < ri)) { rv = ov; ri = oi; }
        }
        int supPar = __shfl(ri, 0);

#pragma unroll
        for (int s2 = 0; s2 < 2; ++s2) {
            int j = lane + s2 * 64;
            if (j < k) sh->parNew[j] = np[s2];
        }
        if (lane == 0) sh->parNew[k] = supPar;
        // rescan columns whose old par was in the cycle (exact recompute)
#pragma unroll
        for (int s2 = 0; s2 < 2; ++s2) {
            int j = lane + s2 * 64;
            if (j < k && np[s2] == -2) {
                int sd = so[s2];
                double bv = DINF; int bi = -1;
                for (int h2 = 0; h2 <= k; ++h2) {
                    double v = sh->mat[sd * STR + sh->ordNew[h2]];
                    if (v < bv) { bv = v; bi = h2; }
                }
                sh->parNew[j] = bi;
            }
        }
        // commit
#pragma unroll
        for (int s2 = 0; s2 < 2; ++s2) {
            int i = lane + s2 * 64;
            if (i <= k) { sh->parIdx[i] = sh->parNew[i]; sh->curOrd[i] = sh->ordNew[i]; }
            sh->inCyc[i] = 0;
        }
        n = k + 1; ++lvl;
    }

    // ---- unwind: packed meta, depth-2 named-register prefetch ----
    int r0 = sh->parIdx[lane], r1 = sh->parIdx[lane + 64];
    int l = lvl - 1;
    int mA0=0,mA1=0,cA0=0,cA1=0, mB0=0,mB1=0,cB0=0,cB1=0;
    if (l >= 0) {
        mA0 = mMeta[l*S+lane]; mA1 = mMeta[l*S+lane+64];
        cA0 = mCyc[l*S+lane];  cA1 = mCyc[l*S+lane+64];
    }
    if (l >= 1) {
        mB0 = mMeta[(l-1)*S+lane]; mB1 = mMeta[(l-1)*S+lane+64];
        cB0 = mCyc[(l-1)*S+lane];  cB1 = mCyc[(l-1)*S+lane+64];
    }
#define UNW_STEP(LM0, LM1, LC0, LC1, LVL_)                                    \
    {                                                                         \
        int kl = sh->hK[LVL_], cl = sh->hC[LVL_];                             \
        int hiSup = gather2(r0, r1, kl);                                      \
        int supM = gather2(LM0, LM1, hiSup & 127);                            \
        int u = supM & 255, vE = (supM >> 8) & 255;                           \
        int g0w = gather2(LM0, LM1, r0 & 127);                                \
        int g1w = gather2(LM0, LM1, r1 & 127);                                \
        int gc0 = gather2(LC0, LC1, lane + 1);                                \
        int gc1 = gather2(LC0, LC1, (lane + 65) & 127);                       \
        int c00 = __shfl(LC0, 0);                                             \
        if (lane == 0) sh->resA[0] = -1;                                      \
        if (lane >= 1 && lane < kl)                                           \
            sh->resA[LM0 & 255] = (r0 == kl) ? ((LM0 >> 16) & 255) : (g0w & 255); \
        if (lane + 64 < kl)                                                   \
            sh->resA[LM1 & 255] = (r1 == kl) ? ((LM1 >> 16) & 255) : (g1w & 255); \
        if (lane < cl) {                                                      \
            int c = LC0; int pn = (lane + 1 < cl) ? gc0 : c00;                \
            sh->resA[c & 127] = (c == vE) ? u : pn;                           \
        }                                                                     \
        if (lane + 64 < cl) {                                                 \
            int c = LC1; int pn = (lane + 65 < cl) ? gc1 : c00;               \
            sh->resA[c & 127] = (c == vE) ? u : pn;                           \
        }                                                                     \
        r0 = sh->resA[lane]; r1 = sh->resA[lane + 64];                        \
    }
    while (l >= 0) {
        {
            int lm0 = mA0, lm1 = mA1, lc0 = cA0, lc1 = cA1;
            if (l >= 2) {
                mA0 = mMeta[(l-2)*S+lane]; mA1 = mMeta[(l-2)*S+lane+64];
                cA0 = mCyc[(l-2)*S+lane];  cA1 = mCyc[(l-2)*S+lane+64];
            }
            UNW_STEP(lm0, lm1, lc0, lc1, l)
        }
        --l;
        if (l < 0) break;
        {
            int lm0 = mB0, lm1 = mB1, lc0 = cB0, lc1 = cB1;
            if (l >= 2) {
                mB0 = mMeta[(l-2)*S+lane]; mB1 = mMeta[(l-2)*S+lane+64];
                cB0 = mCyc[(l-2)*S+lane];  cB1 = mCyc[(l-2)*S+lane+64];
            }
            UNW_STEP(lm0, lm1, lc0, lc1, l)
        }
        --l;
    }
#undef UNW_STEP
    res[lane] = r0; res[lane + 64] = r1;
}

// =======================================================================
// Free-running FW kernel: 24 independent blocks x 64 threads.
// Fused column-per-lane passes; stores obj_b[t] and s-parent history.
// =======================================================================
__global__ void __launch_bounds__(64) fw_kernel(char* __restrict__ ws) {
    const int b = blockIdx.x, lane = threadIdx.x;
    char* base = ws + (size_t)b * PER_BLOCK;
    float* pcT = (float*)(base + OFF_PC);
    const float* featsT = (const float*)(base + OFF_FEATS);
    unsigned int* mMeta = (unsigned int*)(base + OFF_MMETA);
    int* mCyc = (int*)(base + OFF_MCYC);
    double* objG = (double*)(ws + OFF_OBJ) + (size_t)b * 128;
    unsigned char* sParG = (unsigned char*)(ws + OFF_SPAR) + (size_t)b * MAXIT * S;

    __shared__ ShState sh;

    for (int t = 0; t < MAXIT; ++t) {
        // ---- pass A: fused pc-update(t-1) + mode-0 fill + level-0 argmin ----
        float gamma = (t > 0) ? (float)(2.0 / (double)(t + 1)) : 0.0f;
#pragma unroll
        for (int c2 = 0; c2 < 2; ++c2) {
            int col = lane + 64 * c2;
            int sp = (t > 0) ? sh.spar[col] : -1;
            float* pcc = pcT + col * S;
            double* mcol = sh.mat + col * STR;
            float bv = __builtin_inff(); int bi = -1;
#pragma unroll
            for (int i = 0; i < 32; ++i) {
                float4 q = ((float4*)pcc)[i];
                float v0 = q.x, v1 = q.y, v2 = q.z, v3 = q.w;
#define PA_ELEM(VV, EE)                                                       \
                {                                                             \
                    int h = i * 4 + EE;                                       \
                    float pv = VV;                                            \
                    if (t > 0) {                                              \
                        float sv = (sp == h) ? 1.0f : 0.0f;                   \
                        pv = __fadd_rn(pv, __fmul_rn(gamma, __fsub_rn(sv, pv))); \
                        VV = pv;                                              \
                    }                                                         \
                    if (h == col || col == 0) mcol[h] = __builtin_inf();      \
                    else {                                                    \
                        float cv = -pv;                                       \
                        if (cv < bv) { bv = cv; bi = h; }                     \
                        mcol[h] = -(double)pv;                                \
                    }                                                         \
                }
                PA_ELEM(v0, 0) PA_ELEM(v1, 1) PA_ELEM(v2, 2) PA_ELEM(v3, 3)
#undef PA_ELEM
                if (t > 0) { q.x=v0; q.y=v1; q.z=v2; q.w=v3; ((float4*)pcc)[i] = q; }
            }
            sh.parIdx[col] = (col == 0) ? -1 : bi;
            sh.curOrd[col] = col;
            sh.inCyc[col] = 0;
        }
        // p_hat = mst(-pc)
        cle_levels(&sh, mMeta, mCyc, sh.phat);

        // ---- pass B: fused obj + grad fill + level-0 argmin ----
        double acc = 0.0;
#pragma unroll
        for (int c2 = 0; c2 < 2; ++c2) {
            int col = lane + 64 * c2;
            int hp = sh.phat[col];
            const float* fc = featsT + col * S;
            const float* pcc = pcT + col * S;
            double* mcol = sh.mat + col * STR;
            float bv = __builtin_inff(); int bi = -1;
#pragma unroll
            for (int i = 0; i < 32; ++i) {
                float4 f4 = ((const float4*)fc)[i];
                float4 p4 = ((const float4*)pcc)[i];
                float fv0=f4.x, fv1=f4.y, fv2=f4.z, fv3=f4.w;
                float pv0=p4.x, pv1=p4.y, pv2=p4.z, pv3=p4.w;
#define PB_ELEM(FV, PV, EE)                                                   \
                {                                                             \
                    int h = i * 4 + EE;                                       \
                    float ph = (hp == h) ? 1.0f : 0.0f;                       \
                    float diff = __fsub_rn(ph, FV);                           \
                    acc += (double)__fmul_rn(diff, PV);                       \
                    if (h == col || col == 0) mcol[h] = __builtin_inf();      \
                    else {                                                    \
                        float g = __fdiv_rn(diff, 24.0f);                     \
                        if (g < bv) { bv = g; bi = h; }                       \
                        mcol[h] = (double)g;                                  \
                    }                                                         \
                }
                PB_ELEM(fv0, pv0, 0) PB_ELEM(fv1, pv1, 1)
                PB_ELEM(fv2, pv2, 2) PB_ELEM(fv3, pv3, 3)
#undef PB_ELEM
            }
            sh.parIdx[col] = (col == 0) ? -1 : bi;
            sh.curOrd[col] = col;
            sh.inCyc[col] = 0;
        }
        for (int off = 32; off; off >>= 1) acc += __shfl_down(acc, off);
        if (lane == 0) objG[t] = acc;

        // s = mst(grad)
        cle_levels(&sh, mMeta, mCyc, sh.spar);
        sParG[t * S + lane]      = (unsigned char)(sh.spar[lane] & 255);
        sParG[t * S + lane + 64] = (unsigned char)(sh.spar[lane + 64] & 255);
    }
}

// =======================================================================
// Finalize: t* = first argmin of mean obj; replay pc to t*; loss.
// =======================================================================
__global__ void __launch_bounds__(64) fin_kernel(char* __restrict__ ws) {
    const int b = blockIdx.x, lane = threadIdx.x;
    char* base = ws + (size_t)b * PER_BLOCK;
    const float* camT = (const float*)(base + OFF_CAM);
    const double* objG = (const double*)(ws + OFF_OBJ);
    const unsigned char* sParG =
        (const unsigned char*)(ws + OFF_SPAR) + (size_t)b * MAXIT * S;
    double* accAdv = (double*)(ws + OFF_ACC);

    __shared__ float pcL[S * S];
    __shared__ unsigned char sPL[MAXIT * S];

    double v0 = __builtin_inf(), v1 = __builtin_inf();
    if (lane < MAXIT) {
        double s = 0.0;
        for (int bb = 0; bb < BB; ++bb) s += objG[bb * 128 + lane];
        v0 = s / (double)BB;
    }
    if (lane + 64 < MAXIT) {
        double s = 0.0;
        for (int bb = 0; bb < BB; ++bb) s += objG[bb * 128 + lane + 64];
        v1 = s / (double)BB;
    }
    double bv = v0; int bi = lane;
    if (v1 < bv) { bv = v1; bi = lane + 64; }
    for (int off = 32; off; off >>= 1) {
        double ov = __shfl_down(bv, off); int oi = __shfl_down(bi, off);
        if (ov < bv || (ov == bv && oi < bi)) { bv = ov; bi = oi; }
    }
    int tStar = __shfl(bi, 0);

    for (int wgt = lane; wgt < (MAXIT * S) / 4; wgt += 64)
        ((unsigned int*)sPL)[wgt] = ((const unsigned int*)sParG)[wgt];

    for (int i = 0; i < (S * S) / 64; ++i) {
        int idx = i * 64 + lane;
        int d = idx >> 7, h = idx & (S - 1);
        pcL[idx] = (d >= 1 && h == d - 1) ? 1.0f : 0.0f;
    }
    for (int t = 0; t < tStar; ++t) {
        float gamma = (float)(2.0 / (double)(t + 2));
        for (int d = 0; d < S; ++d) {
            int sp = sPL[t * S + d];
            float p0 = pcL[d * S + lane];
            float p1 = pcL[d * S + lane + 64];
            float sv0 = (sp == lane) ? 1.0f : 0.0f;
            float sv1 = (sp == lane + 64) ? 1.0f : 0.0f;
            pcL[d * S + lane]      = __fadd_rn(p0, __fmul_rn(gamma, __fsub_rn(sv0, p0)));
            pcL[d * S + lane + 64] = __fadd_rn(p1, __fmul_rn(gamma, __fsub_rn(sv1, p1)));
        }
    }
    double part = 0.0;
    for (int i = 0; i < (S * S) / 64; ++i) {
        int idx = i * 64 + lane;
        part += (double)__fmul_rn(pcL[idx], camT[idx]);
    }
    for (int off = 32; off; off >>= 1) part += __shfl_down(part, off);
    if (lane == 0) atomicAdd(accAdv, part);
}

__global__ void fin2_kernel(const char* __restrict__ ws, float* __restrict__ out) {
    if (threadIdx.x == 0) {
        const double* acc = (const double*)(ws + OFF_ACC);
        out[0] = (float)((acc[0] - acc[1]) / (double)BB);
    }
}

extern "C" void kernel_launch(void* const* d_in, const int* in_sizes, int n_in,
                              void* d_out, int out_size, void* d_ws, size_t ws_size,
                              hipStream_t stream) {
    const float* s_arc = (const float*)d_in[0];
    const float* s_rel = (const float*)d_in[1];
    const int*   arcs  = (const int*)d_in[2];
    const int*   rels  = (const int*)d_in[3];
    char* ws = (char*)d_ws;

    hipMemsetAsync(ws + OFF_ACC, 0, 16, stream);
    int total = BB * S * S;
    prep_kernel<<<(total + 255) / 256, 256, 0, stream>>>(s_arc, s_rel, arcs, rels, ws);
    fw_kernel<<<dim3(BB), dim3(64), 0, stream>>>(ws);
    fin_kernel<<<dim3(BB), dim3(64), 0, stream>>>(ws);
    fin2_kernel<<<dim3(1), dim3(64), 0, stream>>>(ws, (float*)d_out);
}